// Round 19
// baseline (196.686 us; speedup 1.0000x reference)
//
#include <hip/hip_runtime.h>
#include <math.h>

#define T_ 512
#define J_ 24
#define B_ 8
#define C_ 128
#define N_ (B_*J_)        // 192
#define R_ (N_*T_)        // 98304
#define JC_ (J_*C_)       // 3072
#define BN_EPS 1e-5f

typedef _Float16 half_t;
typedef half_t half8 __attribute__((ext_vector_type(8)));
typedef half_t half4_t __attribute__((ext_vector_type(4)));
typedef float f32x4 __attribute__((ext_vector_type(4)));
typedef unsigned int u32;

__device__ __forceinline__ f32x4 mfma16(half8 a, half8 b, f32x4 c) {
    return __builtin_amdgcn_mfma_f32_16x16x32_f16(a, b, c, 0, 0, 0);
}

// async global->LDS, 16B per lane: dest = wave-uniform l + lane*16
__device__ __forceinline__ void gld16(const void* g, void* l) {
    __builtin_amdgcn_global_load_lds(
        (const __attribute__((address_space(1))) u32*)g,
        (__attribute__((address_space(3))) u32*)l, 16, 0, 0);
}

// x layout: (B, T, J, C). Row r = n*T + t with n = b*J + j.
__device__ __forceinline__ int xbase_n(int n) {
    int b = n / J_;
    int j = n - b * J_;
    return (b * T_ * J_ + j) * C_;     // add t*(J_*C_) + c
}

__device__ __forceinline__ void split2(float x, half_t& h, half_t& l) {
    half_t hh = (half_t)x;
    h = hh;
    l = (half_t)(x - (float)hh);
}

// chunk swizzle for [row][32-half] tiles: spreads the 4 16B chunk slots so
// each consecutive-8-lane phase covers all 8 bank-groups.
__device__ __forceinline__ int phi4(int r) { return (r & 3) ^ ((r >> 2) & 3); }

// Branchless sorted-4 insert (v desc). 4 v_cmp + 14 v_cndmask, no divergence.
__device__ __forceinline__ void ins4b(float (&v)[4], int (&ix)[4], float nv, int ni) {
    bool c0 = nv > v[0], c1 = nv > v[1], c2 = nv > v[2], c3 = nv > v[3];
    float n3 = c2 ? v[2]  : (c3 ? nv : v[3]);
    int   i3 = c2 ? ix[2] : (c3 ? ni : ix[3]);
    float n2 = c1 ? v[1]  : (c2 ? nv : v[2]);
    int   i2 = c1 ? ix[1] : (c2 ? ni : ix[2]);
    float n1 = c0 ? v[0]  : (c1 ? nv : v[1]);
    int   i1 = c0 ? ix[0] : (c1 ? ni : ix[1]);
    float n0 = c0 ? nv : v[0];
    int   i0 = c0 ? ni : ix[0];
    v[0]=n0; v[1]=n1; v[2]=n2; v[3]=n3;
    ix[0]=i0; ix[1]=i1; ix[2]=i2; ix[3]=i3;
}

// compare-exchange: ensure (va,ia) holds the larger (strict <, ties keep order)
__device__ __forceinline__ void ce(float& va, float& vb, int& ia, int& ib) {
    bool c = va < vb;
    float hi = c ? vb : va;
    float lo = c ? va : vb;
    int  ihi = c ? ib : ia;
    int  ilo = c ? ia : ib;
    va = hi; vb = lo; ia = ihi; ib = ilo;
}

// ---------------- Kernel 0: one-time fp16 h/l split of x (+ U/V weights h) --
// xh/xl: [n][kc(4)][s(512)][32], chunk position PRE-SWIZZLED (p ^ phi4(s)).
// Whg: FRAGMENT-CONTIGUOUS [mat][dh][kc][ni][lane][8] so a wave's W-fragment
// load in k_fused is one contiguous 1KB read.
__global__ __launch_bounds__(256) void k_split(const float* __restrict__ x,
        const float* __restrict__ Vw, const float* __restrict__ Uw,
        half_t* __restrict__ xh, half_t* __restrict__ xl,
        half_t* __restrict__ Whg) {
    const int bid = blockIdx.x, tid = threadIdx.x;
    if (bid < 3072) {
        #pragma unroll
        for (int p = 0; p < 4; ++p) {
            int f  = (bid * 4 + p) * 256 + tid;   // float4 id over [r][c4]
            int r  = f >> 5, c4 = f & 31;
            int n  = r >> 9, t = r & 511;
            float4 v = *(const float4*)(x + xbase_n(n) + t * JC_ + (c4 << 2));
            int j = (c4 & 7) >> 1;                // original chunk within k-group
            size_t off = ((size_t)((n << 2) + (c4 >> 3)) * 512 + t) * 32
                       + (((j ^ phi4(t)) << 3) + ((c4 & 1) << 2));
            half_t h0,l0,h1,l1,h2,l2,h3,l3;
            split2(v.x,h0,l0); split2(v.y,h1,l1); split2(v.z,h2,l2); split2(v.w,h3,l3);
            *(half4_t*)&xh[off] = (half4_t){h0,h1,h2,h3};
            *(half4_t*)&xl[off] = (half4_t){l0,l1,l2,l3};
        }
    } else {
        int f = (bid - 3072) * 256 + tid;         // 0..8191 half4 units
        int jj   = f & 1;
        int lane = (f >> 1) & 63;
        int ni   = (f >> 7) & 3;
        int kc   = (f >> 9) & 3;
        int dh   = (f >> 11) & 1;
        int m    = (f >> 12) & 1;
        int d = (dh << 6) + (ni << 4) + (lane & 15);
        int k = (kc << 5) + ((lane >> 4) << 3) + (jj << 2);
        const float* W = m ? Uw : Vw;
        float4 v = *(const float4*)(W + d * C_ + k);
        *(half4_t*)&Whg[(size_t)f * 4] = (half4_t){(half_t)v.x, (half_t)v.y,
                                                   (half_t)v.z, (half_t)v.w};
    }
}

// ---------------- Kernel 1: sim top-4, swapped-operand MFMA, in-reg top4 -----
// UNCHANGED from round 17/18 (70.6us; practical floor for this structure).
__global__ __launch_bounds__(512, 4) void k_sim_topk(const half_t* __restrict__ xh,
        const half_t* __restrict__ xl, int* __restrict__ nbr) {
    __shared__ __align__(16) half_t LB[32768];   // 64 KB: h 32KB | l 32KB
    float* scv = (float*)LB;                     // overlay: 512 float4 (8KB)
    int*   sci = (int*)((char*)LB + 8192);       // overlay: 512 int4   (8KB)

    const int bx = (int)blockIdx.x;              // 0..1535
    const int wg = (bx & 7) * 192 + (bx >> 3);   // XCD-contiguous: 8 blocks/n share L2
    const int n  = wg >> 3;
    const int t0 = (wg & 7) << 6;
    const int tid = threadIdx.x;
    const int lane = tid & 63;
    const int w    = tid >> 6;                   // 0..7
    const int lm   = lane & 15;
    const int lh   = lane >> 4;
    const int lane16 = lane << 4;

    const size_t nb4 = (size_t)(n << 2);

    // loop-invariant fragment offsets (single-buffered slab -> constant)
    int o_s[4], o_t[4];
    #pragma unroll
    for (int si = 0; si < 4; ++si) {
        int rB = (w << 6) + (si << 4) + lm;
        o_s[si] = rB * 32 + ((lh ^ phi4(rB)) << 3);
    }
    #pragma unroll
    for (int ti = 0; ti < 4; ++ti) {
        int rA = t0 + (ti << 4) + lm;
        o_t[ti] = rA * 32 + ((lh ^ phi4(rA)) << 3);
    }
    const half_t* Bh = LB;
    const half_t* Bl = LB + 16384;

    auto stage = [&](int kc) {
        const char* gh = (const char*)xh + (nb4 + kc) * 32768;
        const char* gl = (const char*)xl + (nb4 + kc) * 32768;
        #pragma unroll
        for (int p = 0; p < 4; ++p) {
            const int off = (w * 4 + p) * 1024;  // 32 x 1KB chunks
            gld16(gh + off + lane16, (char*)LB + off);
            gld16(gl + off + lane16, (char*)LB + 32768 + off);
        }
    };

    f32x4 acc[4][4];        // [si][ti]
    #pragma unroll
    for (int si = 0; si < 4; ++si)
        #pragma unroll
        for (int ti = 0; ti < 4; ++ti) acc[si][ti] = (f32x4){0.f,0.f,0.f,0.f};

    #pragma unroll 1
    for (int kc = 0; kc < 4; ++kc) {
        if (kc) __syncthreads();           // all waves done reading prev slab
        stage(kc);
        __syncthreads();                   // vmcnt drain -> slab ready

        half8 s_h[4], s_l[4];
        #pragma unroll
        for (int si = 0; si < 4; ++si) {
            s_h[si] = *(const half8*)&Bh[o_s[si]];
            s_l[si] = *(const half8*)&Bl[o_s[si]];
        }
        #pragma unroll
        for (int ti = 0; ti < 4; ++ti) {
            half8 t_h = *(const half8*)&Bh[o_t[ti]];
            half8 t_l = *(const half8*)&Bl[o_t[ti]];
            #pragma unroll
            for (int si = 0; si < 4; ++si) {
                acc[si][ti] = mfma16(s_h[si], t_h, acc[si][ti]);
                acc[si][ti] = mfma16(s_l[si], t_h, acc[si][ti]);
                acc[si][ti] = mfma16(s_h[si], t_l, acc[si][ti]);
            }
        }
    }
    __syncthreads();                       // slab reads done -> overlay safe

    // ---- in-register top-4 per ti, lh-group merge, cross-wave LDS merge
    const int bidx = (w << 6) + (lh << 2); // + (si<<4) + q
    #pragma unroll
    for (int ti = 0; ti < 4; ++ti) {
        // init from group si=0 via 5-CE sort network (desc)
        float mv[4]; int ix[4];
        #pragma unroll
        for (int q = 0; q < 4; ++q) { mv[q] = acc[0][ti][q]; ix[q] = bidx + q; }
        ce(mv[0], mv[1], ix[0], ix[1]);
        ce(mv[2], mv[3], ix[2], ix[3]);
        ce(mv[0], mv[2], ix[0], ix[2]);
        ce(mv[1], mv[3], ix[1], ix[3]);
        ce(mv[1], mv[2], ix[1], ix[2]);
        // stream groups si=1..3
        #pragma unroll
        for (int si = 1; si < 4; ++si)
            #pragma unroll
            for (int q = 0; q < 4; ++q)
                ins4b(mv, ix, acc[si][ti][q], bidx + (si << 4) + q);
        // merge across the 4 lh lanes of this (lm,ti) row
        #pragma unroll
        for (int st = 16; st <= 32; st <<= 1) {
            float rv[4]; int ri[4];
            #pragma unroll
            for (int q = 0; q < 4; ++q) {
                rv[q] = __shfl_xor(mv[q], st);
                ri[q] = __shfl_xor(ix[q], st);
            }
            #pragma unroll
            for (int q = 0; q < 4; ++q) ins4b(mv, ix, rv[q], ri[q]);
        }
        if (lh == 0) {
            int row = (ti << 4) + lm;
            int idx = (row << 3) + (w ^ (row & 7));     // bank-spread slot
            *(float4*)(scv + (idx << 2)) = make_float4(mv[0], mv[1], mv[2], mv[3]);
            *(int4*)  (sci + (idx << 2)) = make_int4(ix[0], ix[1], ix[2], ix[3]);
        }
    }
    __syncthreads();

    // ---- final: 8 threads per row merge the 8 wave-windows
    {
        int row = tid >> 3, g = tid & 7;
        int idx = (row << 3) + (g ^ (row & 7));         // bank-spread read
        float4 v4 = *(const float4*)(scv + (idx << 2));
        int4   i4 = *(const int4*)  (sci + (idx << 2));
        float fv[4] = {v4.x, v4.y, v4.z, v4.w};
        int   fi[4] = {i4.x, i4.y, i4.z, i4.w};
        #pragma unroll
        for (int st = 1; st <= 4; st <<= 1) {
            float rv[4]; int ri[4];
            #pragma unroll
            for (int q = 0; q < 4; ++q) {
                rv[q] = __shfl_xor(fv[q], st);
                ri[q] = __shfl_xor(fi[q], st);
            }
            #pragma unroll
            for (int q = 0; q < 4; ++q) ins4b(fv, fi, rv[q], ri[q]);
        }
        if (g == 0) {
            int r = n * T_ + t0 + row;
            *(int4*)(nbr + (size_t)r * 4) = make_int4(fi[0], fi[1], fi[2], fi[3]);
        }
    }
}

// ---------------- Kernel 2 (fused): vx+ux GEMMs + LDS gather + BN partials ---
// One block per (n, d-half). ZERO-LDS-staging GEMM: X fragments have zero
// reuse (each 16B chunk -> exactly one lane) so they load straight from
// global; W fragments load from the fragment-contiguous Whg (L1-served 8x
// reuse). V and U phases run sequentially reusing one acc[4][4] (64 AGPR)
// -> fits 128-reg cap -> 2 blocks/CU. No barriers in the GEMM loops.
__global__ __launch_bounds__(512, 4) void k_fused(const half_t* __restrict__ xh,
        const half_t* __restrict__ Whg,
        const float* __restrict__ Vb, const float* __restrict__ Ub,
        const int* __restrict__ nbr, half_t* __restrict__ preh,
        float* __restrict__ stats) {
    __shared__ __align__(16) half_t VXL[512 * 64];  // 64KB: vx fp16 [row][lm][ni]
    __shared__ float red[1024];                     // 4KB reduction buffer

    const int bx  = (int)blockIdx.x;
    const int xcd = bx & 7;
    const int dh  = (bx >> 3) & 1;
    const int n   = ((bx >> 4) << 3) | xcd;

    const int tid  = threadIdx.x;
    const int lane = tid & 63;
    const int w    = tid >> 6;
    const int lm   = lane & 15;
    const int lh   = lane >> 4;

    const size_t nb4 = (size_t)(n << 2);

    // X fragment offsets within a kc slab (constant across kc)
    int xo[4];
    #pragma unroll
    for (int mi = 0; mi < 4; ++mi) {
        int rA = (w << 6) + (mi << 4) + lm;
        xo[mi] = rA * 32 + ((lh ^ phi4(rA)) << 3);
    }
    // Whg layout [mat][dh][kc][ni][lane][8]: strides in halves
    const half_t* WV = Whg + (size_t)dh * 8192;            // mat=0
    const half_t* WU = Whg + 16384 + (size_t)dh * 8192;    // mat=1
    const int lane8 = lane << 3;

    f32x4 acc[4][4];
    #pragma unroll
    for (int mi = 0; mi < 4; ++mi)
        #pragma unroll
        for (int ni = 0; ni < 4; ++ni) acc[mi][ni] = (f32x4){0.f,0.f,0.f,0.f};

    // ---- V phase (no LDS, no barriers)
    #pragma unroll 1
    for (int kc = 0; kc < 4; ++kc) {
        const half_t* xb = xh + (nb4 + kc) * 16384;
        half8 ax[4];
        #pragma unroll
        for (int mi = 0; mi < 4; ++mi) ax[mi] = *(const half8*)(xb + xo[mi]);
        const half_t* wb = WV + kc * 2048;
        #pragma unroll
        for (int ni = 0; ni < 4; ++ni) {
            half8 bw = *(const half8*)(wb + ni * 512 + lane8);
            #pragma unroll
            for (int mi = 0; mi < 4; ++mi)
                acc[mi][ni] = mfma16(ax[mi], bw, acc[mi][ni]);
        }
    }
    // dump vx -> VXL transposed [row][lm][ni], stride 64
    #pragma unroll
    for (int mi = 0; mi < 4; ++mi)
        #pragma unroll
        for (int q = 0; q < 4; ++q) {
            int row = (w << 6) + (mi << 4) + (lh << 2) + q;
            half4_t vv = { (half_t)acc[mi][0][q], (half_t)acc[mi][1][q],
                           (half_t)acc[mi][2][q], (half_t)acc[mi][3][q] };
            *(half4_t*)&VXL[(row << 6) + (lm << 2)] = vv;
        }
    // ---- U phase (acc reused)
    #pragma unroll
    for (int mi = 0; mi < 4; ++mi)
        #pragma unroll
        for (int ni = 0; ni < 4; ++ni) acc[mi][ni] = (f32x4){0.f,0.f,0.f,0.f};
    #pragma unroll 1
    for (int kc = 0; kc < 4; ++kc) {
        const half_t* xb = xh + (nb4 + kc) * 16384;
        half8 ax[4];
        #pragma unroll
        for (int mi = 0; mi < 4; ++mi) ax[mi] = *(const half8*)(xb + xo[mi]);
        const half_t* wb = WU + kc * 2048;
        #pragma unroll
        for (int ni = 0; ni < 4; ++ni) {
            half8 bw = *(const half8*)(wb + ni * 512 + lane8);
            #pragma unroll
            for (int mi = 0; mi < 4; ++mi)
                acc[mi][ni] = mfma16(ax[mi], bw, acc[mi][ni]);
        }
    }
    __syncthreads();                       // all VXL dumps visible

    // ---- gather (vectorized half4 per neighbor row, nbr via global bcast)
    float bsum[4];
    #pragma unroll
    for (int ni = 0; ni < 4; ++ni) {
        int col = (ni << 4) + lm;
        bsum[ni] = Vb[(dh << 6) + col] + Ub[(dh << 6) + col];
    }
    float sc[4] = {0,0,0,0}, sq2[4] = {0,0,0,0};
    #pragma unroll
    for (int mi = 0; mi < 4; ++mi) {
        #pragma unroll
        for (int q = 0; q < 4; ++q) {
            int row = (w << 6) + (mi << 4) + (lh << 2) + q;
            int4 nb = *(const int4*)(nbr + ((((size_t)n << 9) + row) << 2));
            half4_t g0 = *(const half4_t*)&VXL[(nb.x << 6) + (lm << 2)];
            half4_t g1 = *(const half4_t*)&VXL[(nb.y << 6) + (lm << 2)];
            half4_t g2 = *(const half4_t*)&VXL[(nb.z << 6) + (lm << 2)];
            half4_t g3 = *(const half4_t*)&VXL[(nb.w << 6) + (lm << 2)];
            size_t rb = ((((size_t)n << 9) + row) << 7) + (dh << 6);
            #pragma unroll
            for (int ni = 0; ni < 4; ++ni) {
                float g = (float)g0[ni] + (float)g1[ni] + (float)g2[ni] + (float)g3[ni];
                float o = acc[mi][ni][q] + bsum[ni] + 0.25f * g;
                preh[rb + (ni << 4) + lm] = (half_t)o;
                sc[ni] += o; sq2[ni] += o * o;
            }
        }
    }
    #pragma unroll
    for (int ni = 0; ni < 4; ++ni) {
        sc[ni]  += __shfl_xor(sc[ni], 16);  sc[ni]  += __shfl_xor(sc[ni], 32);
        sq2[ni] += __shfl_xor(sq2[ni], 16); sq2[ni] += __shfl_xor(sq2[ni], 32);
    }
    if (lh == 0) {
        #pragma unroll
        for (int ni = 0; ni < 4; ++ni) {
            red[(w * 16 + lm) * 8 + ni * 2 + 0] = sc[ni];
            red[(w * 16 + lm) * 8 + ni * 2 + 1] = sq2[ni];
        }
    }
    __syncthreads();
    if (tid < 128) {
        int col = tid >> 1, st = tid & 1;          // col 0..63 within half
        int lmm = col & 15, nii = col >> 4;
        float a = 0.f;
        #pragma unroll
        for (int g = 0; g < 8; ++g) a += red[(g * 16 + lmm) * 8 + nii * 2 + st];
        atomicAdd(stats + st * 128 + (dh << 6) + col, a);
    }
}

// ---------------- Kernel 4: BN normalize + residual + ReLU + transpose --------
// Residual read from xh (h = fp16(x)); UNCHANGED from round 17/18.
__global__ __launch_bounds__(256) void k_fin(const half_t* __restrict__ xh,
        const half_t* __restrict__ preh, const float* __restrict__ stats,
        const float* __restrict__ gamma, const float* __restrict__ beta,
        float* __restrict__ out) {
    const int id = blockIdx.x * 256 + threadIdx.x;   // float4 id
    const int r  = id >> 5;
    const int c0 = (id & 31) << 2;
    const float inv = 1.0f / (float)R_;
    float4 s  = *(const float4*)(stats + c0);
    float4 sq = *(const float4*)(stats + 128 + c0);
    float4 g  = *(const float4*)(gamma + c0);
    float4 bt = *(const float4*)(beta + c0);
    float m0 = s.x*inv, m1 = s.y*inv, m2 = s.z*inv, m3 = s.w*inv;
    float sc0 = g.x * rsqrtf(sq.x*inv - m0*m0 + BN_EPS);
    float sc1 = g.y * rsqrtf(sq.y*inv - m1*m1 + BN_EPS);
    float sc2 = g.z * rsqrtf(sq.z*inv - m2*m2 + BN_EPS);
    float sc3 = g.w * rsqrtf(sq.w*inv - m3*m3 + BN_EPS);
    float sh0 = bt.x - m0*sc0, sh1 = bt.y - m1*sc1;
    float sh2 = bt.z - m2*sc2, sh3 = bt.w - m3*sc3;
    int n = r >> 9, t = r & 511;
    // xh fetch: [n][kc][s][32] chunk-pre-swizzled, c0 4-aligned
    int kc = c0 >> 5, ce2 = c0 & 31, j = ce2 >> 3, sub = ce2 & 7;
    size_t hoff = ((size_t)((n << 2) + kc) * 512 + t) * 32
                + ((j ^ phi4(t)) << 3) + sub;
    half4_t xv = *(const half4_t*)(xh + hoff);
    half4_t ph = *(const half4_t*)(preh + (size_t)r*C_ + c0);
    int off = xbase_n(n) + t*(J_*C_) + c0;
    float4 y;
    y.x = (float)xv[0] + (float)ph[0]*sc0 + sh0;
    y.y = (float)xv[1] + (float)ph[1]*sc1 + sh1;
    y.z = (float)xv[2] + (float)ph[2]*sc2 + sh2;
    y.w = (float)xv[3] + (float)ph[3]*sc3 + sh3;
    y.x = y.x > 0.f ? y.x : 0.f; y.y = y.y > 0.f ? y.y : 0.f;
    y.z = y.z > 0.f ? y.z : 0.f; y.w = y.w > 0.f ? y.w : 0.f;
    *(float4*)(out + off) = y;
}

extern "C" void kernel_launch(void* const* d_in, const int* in_sizes, int n_in,
                              void* d_out, int out_size, void* d_ws, size_t ws_size,
                              hipStream_t stream) {
    const float* x     = (const float*)d_in[0];
    const float* Uw    = (const float*)d_in[1];
    const float* Ub    = (const float*)d_in[2];
    const float* Vw    = (const float*)d_in[3];
    const float* Vb    = (const float*)d_in[4];
    const float* gamma = (const float*)d_in[5];
    const float* beta  = (const float*)d_in[6];
    float* out = (float*)d_out;

    // workspace: preh (R*C f16) | nbr (R*4 i32) | stats (256 f32) |
    //            xh (R*C f16) | xl (R*C f16) | Whg (2*C*C f16)
    half_t* preh  = (half_t*)d_ws;
    int*    nbr   = (int*)(preh + (size_t)R_ * C_);
    float*  stats = (float*)(nbr + (size_t)R_ * 4);
    half_t* xh    = (half_t*)(stats + 256);
    half_t* xl    = xh + (size_t)R_ * C_;
    half_t* Whg   = xl + (size_t)R_ * C_;

    hipMemsetAsync(stats, 0, 256 * sizeof(float), stream);
    k_split<<<3104, 256, 0, stream>>>(x, Vw, Uw, xh, xl, Whg);
    k_sim_topk<<<N_ * 8, 512, 0, stream>>>(xh, xl, nbr);
    k_fused<<<384, 512, 0, stream>>>(xh, Whg, Vb, Ub, nbr, preh, stats);
    k_fin<<<(R_ * 32) / 256, 256, 0, stream>>>(xh, preh, stats, gamma, beta, out);
}

// Round 20
// 130.030 us; speedup vs baseline: 1.5126x; 1.5126x over previous
//
#include <hip/hip_runtime.h>
#include <math.h>

#define T_ 512
#define J_ 24
#define B_ 8
#define C_ 128
#define N_ (B_*J_)        // 192
#define R_ (N_*T_)        // 98304
#define JC_ (J_*C_)       // 3072
#define BN_EPS 1e-5f

typedef _Float16 half_t;
typedef half_t half8 __attribute__((ext_vector_type(8)));
typedef half_t half4_t __attribute__((ext_vector_type(4)));
typedef float f32x4 __attribute__((ext_vector_type(4)));
typedef unsigned int u32;

__device__ __forceinline__ f32x4 mfma16(half8 a, half8 b, f32x4 c) {
    return __builtin_amdgcn_mfma_f32_16x16x32_f16(a, b, c, 0, 0, 0);
}

// async global->LDS, 16B per lane: dest = wave-uniform l + lane*16
__device__ __forceinline__ void gld16(const void* g, void* l) {
    __builtin_amdgcn_global_load_lds(
        (const __attribute__((address_space(1))) u32*)g,
        (__attribute__((address_space(3))) u32*)l, 16, 0, 0);
}

// x layout: (B, T, J, C). Row r = n*T + t with n = b*J + j.
__device__ __forceinline__ int xbase_n(int n) {
    int b = n / J_;
    int j = n - b * J_;
    return (b * T_ * J_ + j) * C_;     // add t*(J_*C_) + c
}

__device__ __forceinline__ void split2(float x, half_t& h, half_t& l) {
    half_t hh = (half_t)x;
    h = hh;
    l = (half_t)(x - (float)hh);
}

// chunk swizzle for [row][32-half] tiles: spreads the 4 16B chunk slots so
// each consecutive-8-lane phase covers all 8 bank-groups.
__device__ __forceinline__ int phi4(int r) { return (r & 3) ^ ((r >> 2) & 3); }

// Branchless sorted-4 insert (v desc). 4 v_cmp + 14 v_cndmask, no divergence.
__device__ __forceinline__ void ins4b(float (&v)[4], int (&ix)[4], float nv, int ni) {
    bool c0 = nv > v[0], c1 = nv > v[1], c2 = nv > v[2], c3 = nv > v[3];
    float n3 = c2 ? v[2]  : (c3 ? nv : v[3]);
    int   i3 = c2 ? ix[2] : (c3 ? ni : ix[3]);
    float n2 = c1 ? v[1]  : (c2 ? nv : v[2]);
    int   i2 = c1 ? ix[1] : (c2 ? ni : ix[2]);
    float n1 = c0 ? v[0]  : (c1 ? nv : v[1]);
    int   i1 = c0 ? ix[0] : (c1 ? ni : ix[1]);
    float n0 = c0 ? nv : v[0];
    int   i0 = c0 ? ni : ix[0];
    v[0]=n0; v[1]=n1; v[2]=n2; v[3]=n3;
    ix[0]=i0; ix[1]=i1; ix[2]=i2; ix[3]=i3;
}

// compare-exchange: ensure (va,ia) holds the larger (strict <, ties keep order)
__device__ __forceinline__ void ce(float& va, float& vb, int& ia, int& ib) {
    bool c = va < vb;
    float hi = c ? vb : va;
    float lo = c ? va : vb;
    int  ihi = c ? ib : ia;
    int  ilo = c ? ia : ib;
    va = hi; vb = lo; ia = ihi; ib = ilo;
}

// ---------------- Kernel 0: one-time fp16 h/l split of x (+ U/V weights h) --
// xh/xl layout: [n][kc(4)][s(512)][32] with chunk position PRE-SWIZZLED:
// position p of row s holds original chunk p ^ phi4(s).
__global__ __launch_bounds__(256) void k_split(const float* __restrict__ x,
        const float* __restrict__ Vw, const float* __restrict__ Uw,
        half_t* __restrict__ xh, half_t* __restrict__ xl,
        half_t* __restrict__ Whg) {
    const int bid = blockIdx.x, tid = threadIdx.x;
    if (bid < 3072) {
        #pragma unroll
        for (int p = 0; p < 4; ++p) {
            int f  = (bid * 4 + p) * 256 + tid;   // float4 id over [r][c4]
            int r  = f >> 5, c4 = f & 31;
            int n  = r >> 9, t = r & 511;
            float4 v = *(const float4*)(x + xbase_n(n) + t * JC_ + (c4 << 2));
            int j = (c4 & 7) >> 1;                // original chunk within k-group
            size_t off = ((size_t)((n << 2) + (c4 >> 3)) * 512 + t) * 32
                       + (((j ^ phi4(t)) << 3) + ((c4 & 1) << 2));
            half_t h0,l0,h1,l1,h2,l2,h3,l3;
            split2(v.x,h0,l0); split2(v.y,h1,l1); split2(v.z,h2,l2); split2(v.w,h3,l3);
            *(half4_t*)&xh[off] = (half4_t){h0,h1,h2,h3};
            *(half4_t*)&xl[off] = (half4_t){l0,l1,l2,l3};
        }
    } else {
        int f  = (bid - 3072) * 256 + tid;        // 0..8191
        int m  = f >> 12;                          // 0=V, 1=U
        int fl = f & 4095;
        int row = fl >> 5, c4 = fl & 31;
        const float* W = m ? Uw : Vw;
        float4 v = *(const float4*)(W + row * C_ + (c4 << 2));
        int off = (m * 128 + row) * 128 + (c4 << 2);
        *(half4_t*)&Whg[off] = (half4_t){(half_t)v.x, (half_t)v.y,
                                         (half_t)v.z, (half_t)v.w};
    }
}

// ---------------- Kernel 1: sim top-4, swapped-operand MFMA, in-reg top4 -----
// UNCHANGED (70.6us; practical floor for this structure).
__global__ __launch_bounds__(512, 4) void k_sim_topk(const half_t* __restrict__ xh,
        const half_t* __restrict__ xl, int* __restrict__ nbr) {
    __shared__ __align__(16) half_t LB[32768];   // 64 KB: h 32KB | l 32KB
    float* scv = (float*)LB;                     // overlay: 512 float4 (8KB)
    int*   sci = (int*)((char*)LB + 8192);       // overlay: 512 int4   (8KB)

    const int bx = (int)blockIdx.x;              // 0..1535
    const int wg = (bx & 7) * 192 + (bx >> 3);   // XCD-contiguous: 8 blocks/n share L2
    const int n  = wg >> 3;
    const int t0 = (wg & 7) << 6;
    const int tid = threadIdx.x;
    const int lane = tid & 63;
    const int w    = tid >> 6;                   // 0..7
    const int lm   = lane & 15;
    const int lh   = lane >> 4;
    const int lane16 = lane << 4;

    const size_t nb4 = (size_t)(n << 2);

    // loop-invariant fragment offsets (single-buffered slab -> constant)
    int o_s[4], o_t[4];
    #pragma unroll
    for (int si = 0; si < 4; ++si) {
        int rB = (w << 6) + (si << 4) + lm;
        o_s[si] = rB * 32 + ((lh ^ phi4(rB)) << 3);
    }
    #pragma unroll
    for (int ti = 0; ti < 4; ++ti) {
        int rA = t0 + (ti << 4) + lm;
        o_t[ti] = rA * 32 + ((lh ^ phi4(rA)) << 3);
    }
    const half_t* Bh = LB;
    const half_t* Bl = LB + 16384;

    auto stage = [&](int kc) {
        const char* gh = (const char*)xh + (nb4 + kc) * 32768;
        const char* gl = (const char*)xl + (nb4 + kc) * 32768;
        #pragma unroll
        for (int p = 0; p < 4; ++p) {
            const int off = (w * 4 + p) * 1024;  // 32 x 1KB chunks
            gld16(gh + off + lane16, (char*)LB + off);
            gld16(gl + off + lane16, (char*)LB + 32768 + off);
        }
    };

    f32x4 acc[4][4];        // [si][ti]
    #pragma unroll
    for (int si = 0; si < 4; ++si)
        #pragma unroll
        for (int ti = 0; ti < 4; ++ti) acc[si][ti] = (f32x4){0.f,0.f,0.f,0.f};

    #pragma unroll 1
    for (int kc = 0; kc < 4; ++kc) {
        if (kc) __syncthreads();           // all waves done reading prev slab
        stage(kc);
        __syncthreads();                   // vmcnt drain -> slab ready

        half8 s_h[4], s_l[4];
        #pragma unroll
        for (int si = 0; si < 4; ++si) {
            s_h[si] = *(const half8*)&Bh[o_s[si]];
            s_l[si] = *(const half8*)&Bl[o_s[si]];
        }
        #pragma unroll
        for (int ti = 0; ti < 4; ++ti) {
            half8 t_h = *(const half8*)&Bh[o_t[ti]];
            half8 t_l = *(const half8*)&Bl[o_t[ti]];
            #pragma unroll
            for (int si = 0; si < 4; ++si) {
                acc[si][ti] = mfma16(s_h[si], t_h, acc[si][ti]);
                acc[si][ti] = mfma16(s_l[si], t_h, acc[si][ti]);
                acc[si][ti] = mfma16(s_h[si], t_l, acc[si][ti]);
            }
        }
    }
    __syncthreads();                       // slab reads done -> overlay safe

    // ---- in-register top-4 per ti, lh-group merge, cross-wave LDS merge
    const int bidx = (w << 6) + (lh << 2); // + (si<<4) + q
    #pragma unroll
    for (int ti = 0; ti < 4; ++ti) {
        // init from group si=0 via 5-CE sort network (desc)
        float mv[4]; int ix[4];
        #pragma unroll
        for (int q = 0; q < 4; ++q) { mv[q] = acc[0][ti][q]; ix[q] = bidx + q; }
        ce(mv[0], mv[1], ix[0], ix[1]);
        ce(mv[2], mv[3], ix[2], ix[3]);
        ce(mv[0], mv[2], ix[0], ix[2]);
        ce(mv[1], mv[3], ix[1], ix[3]);
        ce(mv[1], mv[2], ix[1], ix[2]);
        // stream groups si=1..3
        #pragma unroll
        for (int si = 1; si < 4; ++si)
            #pragma unroll
            for (int q = 0; q < 4; ++q)
                ins4b(mv, ix, acc[si][ti][q], bidx + (si << 4) + q);
        // merge across the 4 lh lanes of this (lm,ti) row
        #pragma unroll
        for (int st = 16; st <= 32; st <<= 1) {
            float rv[4]; int ri[4];
            #pragma unroll
            for (int q = 0; q < 4; ++q) {
                rv[q] = __shfl_xor(mv[q], st);
                ri[q] = __shfl_xor(ix[q], st);
            }
            #pragma unroll
            for (int q = 0; q < 4; ++q) ins4b(mv, ix, rv[q], ri[q]);
        }
        if (lh == 0) {
            int row = (ti << 4) + lm;
            int idx = (row << 3) + (w ^ (row & 7));     // bank-spread slot
            *(float4*)(scv + (idx << 2)) = make_float4(mv[0], mv[1], mv[2], mv[3]);
            *(int4*)  (sci + (idx << 2)) = make_int4(ix[0], ix[1], ix[2], ix[3]);
        }
    }
    __syncthreads();

    // ---- final: 8 threads per row merge the 8 wave-windows
    {
        int row = tid >> 3, g = tid & 7;
        int idx = (row << 3) + (g ^ (row & 7));         // bank-spread read
        float4 v4 = *(const float4*)(scv + (idx << 2));
        int4   i4 = *(const int4*)  (sci + (idx << 2));
        float fv[4] = {v4.x, v4.y, v4.z, v4.w};
        int   fi[4] = {i4.x, i4.y, i4.z, i4.w};
        #pragma unroll
        for (int st = 1; st <= 4; st <<= 1) {
            float rv[4]; int ri[4];
            #pragma unroll
            for (int q = 0; q < 4; ++q) {
                rv[q] = __shfl_xor(fv[q], st);
                ri[q] = __shfl_xor(fi[q], st);
            }
            #pragma unroll
            for (int q = 0; q < 4; ++q) ins4b(fv, fi, rv[q], ri[q]);
        }
        if (g == 0) {
            int r = n * T_ + t0 + row;
            *(int4*)(nbr + (size_t)r * 4) = make_int4(fi[0], fi[1], fi[2], fi[3]);
        }
    }
}

// ---------------- Kernel 2 (fused): vx+ux GEMMs + LDS gather + BN partials ---
// One block per (n, d-half). H-ONLY GEMM; pre written fp16 (stats fp32).
// VXL stored TRANSPOSED [row][lm(16)][ni(4)] (stride 72 halves) so the
// gather reads one neighbor's 4 ni values as a contiguous half4 (8B).
// REVERTED to round-18 (reg-staged coalesced X/W via LDS): zero-staging
// variant (r19) lost 4x on read coalescing + 8x write amplification.
__global__ __launch_bounds__(512) void k_fused(const half_t* __restrict__ xh,
        const half_t* __restrict__ Whg,
        const float* __restrict__ Vb, const float* __restrict__ Ub,
        const int* __restrict__ nbr, half_t* __restrict__ preh,
        float* __restrict__ stats) {
    __shared__ __align__(16) half_t XB[16384];      // 32KB: Xh[512*32]
    __shared__ __align__(16) half_t WC[4096];       // 8KB:  Wh[128*32]
    __shared__ __align__(16) half_t VXL[512 * 72];  // 72KB: vx fp16 [row][lm][ni]

    const int bx  = (int)blockIdx.x;
    const int xcd = bx & 7;
    const int dh  = (bx >> 3) & 1;
    const int n   = ((bx >> 4) << 3) | xcd;

    const int tid  = threadIdx.x;
    const int lane = tid & 63;
    const int w    = tid >> 6;
    const int lm   = lane & 15;
    const int lh   = lane >> 4;

    const size_t nb4 = (size_t)(n << 2);
    half8 pXh[4], pWh;

    auto issueX = [&](int kc) {
        #pragma unroll
        for (int p = 0; p < 4; ++p) {
            int f = tid + (p << 9);
            int r = f >> 2, j = f & 3;
            pXh[p] = *(const half8*)(xh + ((nb4 + kc) * 512 + r) * 32 + (j << 3));
        }
    };
    auto issueW = [&](int kc) {
        int wrow = tid >> 2, kq = tid & 3;           // 128 rows x 4 chunks
        int mat = wrow >> 6, dd = wrow & 63;
        size_t so = (size_t)(mat * 128 + (dh << 6) + dd) * 128 + (kc << 5) + (kq << 3);
        pWh = *(const half8*)(Whg + so);
    };
    auto commitX = [&]() {
        #pragma unroll
        for (int p = 0; p < 4; ++p) {
            int f = tid + (p << 9);
            int r = f >> 2, j = f & 3;
            *(half8*)&XB[r * 32 + (j << 3)] = pXh[p];   // LINEAR: pre-swizzled
        }
    };
    auto commitW = [&]() {
        int wrow = tid >> 2, kq = tid & 3;
        *(half8*)&WC[wrow * 32 + ((kq ^ phi4(wrow)) << 3)] = pWh;
    };

    f32x4 acc[2][4][4];     // [mat(V,U)][mi][ni]
    #pragma unroll
    for (int m = 0; m < 2; ++m)
        #pragma unroll
        for (int mi = 0; mi < 4; ++mi)
            #pragma unroll
            for (int ni = 0; ni < 4; ++ni) acc[m][mi][ni] = (f32x4){0.f,0.f,0.f,0.f};

    issueX(0); issueW(0);
    commitX(); commitW();
    __syncthreads();

    #pragma unroll 1
    for (int kc = 0; kc < 4; ++kc) {
        if (kc < 3) { issueX(kc + 1); issueW(kc + 1); }

        half8 ah[4];
        #pragma unroll
        for (int mi = 0; mi < 4; ++mi) {
            int row = (w << 6) + (mi << 4) + lm;
            ah[mi] = *(const half8*)&XB[row * 32 + ((lh ^ phi4(row)) << 3)];
        }
        #pragma unroll
        for (int mat = 0; mat < 2; ++mat) {
            #pragma unroll
            for (int ni = 0; ni < 4; ++ni) {
                int wrow = (mat << 6) + (ni << 4) + lm;
                half8 bh = *(const half8*)&WC[wrow * 32 + ((lh ^ phi4(wrow)) << 3)];
                #pragma unroll
                for (int mi = 0; mi < 4; ++mi)
                    acc[mat][mi][ni] = mfma16(ah[mi], bh, acc[mat][mi][ni]);
            }
        }
        if (kc < 3) {
            __syncthreads();
            commitX(); commitW();
        }
        __syncthreads();
    }

    // ---- dump vx (mat 0) to LDS fp16, transposed [row][lm][ni]; nbr -> XB
    #pragma unroll
    for (int mi = 0; mi < 4; ++mi)
        #pragma unroll
        for (int q = 0; q < 4; ++q) {
            int row = (w << 6) + (mi << 4) + (lh << 2) + q;
            half4_t vv = { (half_t)acc[0][mi][0][q], (half_t)acc[0][mi][1][q],
                           (half_t)acc[0][mi][2][q], (half_t)acc[0][mi][3][q] };
            *(half4_t*)&VXL[row * 72 + (lm << 2)] = vv;
        }
    int4* nbl = (int4*)XB;                         // 8KB
    float* red = (float*)(XB + 4096);              // +8KB bytes, 4KB used
    nbl[tid] = *(const int4*)(nbr + ((((size_t)n << 9) + tid) << 2));
    __syncthreads();

    // ---- gather (vectorized half4 per neighbor row) + epilogue
    float bsum[4];
    #pragma unroll
    for (int ni = 0; ni < 4; ++ni) {
        int col = (ni << 4) + lm;
        bsum[ni] = Vb[(dh << 6) + col] + Ub[(dh << 6) + col];
    }
    float sc[4] = {0,0,0,0}, sq2[4] = {0,0,0,0};
    #pragma unroll
    for (int mi = 0; mi < 4; ++mi) {
        #pragma unroll
        for (int q = 0; q < 4; ++q) {
            int row = (w << 6) + (mi << 4) + (lh << 2) + q;
            int4 nb = nbl[row];
            half4_t g0 = *(const half4_t*)&VXL[nb.x * 72 + (lm << 2)];
            half4_t g1 = *(const half4_t*)&VXL[nb.y * 72 + (lm << 2)];
            half4_t g2 = *(const half4_t*)&VXL[nb.z * 72 + (lm << 2)];
            half4_t g3 = *(const half4_t*)&VXL[nb.w * 72 + (lm << 2)];
            size_t rb = ((((size_t)n << 9) + row) << 7) + (dh << 6);
            #pragma unroll
            for (int ni = 0; ni < 4; ++ni) {
                float g = (float)g0[ni] + (float)g1[ni] + (float)g2[ni] + (float)g3[ni];
                float o = acc[1][mi][ni][q] + bsum[ni] + 0.25f * g;
                preh[rb + (ni << 4) + lm] = (half_t)o;
                sc[ni] += o; sq2[ni] += o * o;
            }
        }
    }
    #pragma unroll
    for (int ni = 0; ni < 4; ++ni) {
        sc[ni]  += __shfl_xor(sc[ni], 16);  sc[ni]  += __shfl_xor(sc[ni], 32);
        sq2[ni] += __shfl_xor(sq2[ni], 16); sq2[ni] += __shfl_xor(sq2[ni], 32);
    }
    if (lh == 0) {
        #pragma unroll
        for (int ni = 0; ni < 4; ++ni) {
            red[(w * 16 + lm) * 8 + ni * 2 + 0] = sc[ni];
            red[(w * 16 + lm) * 8 + ni * 2 + 1] = sq2[ni];
        }
    }
    __syncthreads();
    if (tid < 128) {
        int col = tid >> 1, st = tid & 1;          // col 0..63 within half
        int lmm = col & 15, nii = col >> 4;
        float a = 0.f;
        #pragma unroll
        for (int g = 0; g < 8; ++g) a += red[(g * 16 + lmm) * 8 + nii * 2 + st];
        atomicAdd(stats + st * 128 + (dh << 6) + col, a);
    }
}

// ---------------- Kernel 4: BN normalize + residual + ReLU + transpose --------
// Residual read from xh (h = fp16(x)); UNCHANGED from round 17/18.
__global__ __launch_bounds__(256) void k_fin(const half_t* __restrict__ xh,
        const half_t* __restrict__ preh, const float* __restrict__ stats,
        const float* __restrict__ gamma, const float* __restrict__ beta,
        float* __restrict__ out) {
    const int id = blockIdx.x * 256 + threadIdx.x;   // float4 id
    const int r  = id >> 5;
    const int c0 = (id & 31) << 2;
    const float inv = 1.0f / (float)R_;
    float4 s  = *(const float4*)(stats + c0);
    float4 sq = *(const float4*)(stats + 128 + c0);
    float4 g  = *(const float4*)(gamma + c0);
    float4 bt = *(const float4*)(beta + c0);
    float m0 = s.x*inv, m1 = s.y*inv, m2 = s.z*inv, m3 = s.w*inv;
    float sc0 = g.x * rsqrtf(sq.x*inv - m0*m0 + BN_EPS);
    float sc1 = g.y * rsqrtf(sq.y*inv - m1*m1 + BN_EPS);
    float sc2 = g.z * rsqrtf(sq.z*inv - m2*m2 + BN_EPS);
    float sc3 = g.w * rsqrtf(sq.w*inv - m3*m3 + BN_EPS);
    float sh0 = bt.x - m0*sc0, sh1 = bt.y - m1*sc1;
    float sh2 = bt.z - m2*sc2, sh3 = bt.w - m3*sc3;
    int n = r >> 9, t = r & 511;
    // xh fetch: [n][kc][s][32] chunk-pre-swizzled, c0 4-aligned
    int kc = c0 >> 5, ce2 = c0 & 31, j = ce2 >> 3, sub = ce2 & 7;
    size_t hoff = ((size_t)((n << 2) + kc) * 512 + t) * 32
                + ((j ^ phi4(t)) << 3) + sub;
    half4_t xv = *(const half4_t*)(xh + hoff);
    half4_t ph = *(const half4_t*)(preh + (size_t)r*C_ + c0);
    int off = xbase_n(n) + t*(J_*C_) + c0;
    float4 y;
    y.x = (float)xv[0] + (float)ph[0]*sc0 + sh0;
    y.y = (float)xv[1] + (float)ph[1]*sc1 + sh1;
    y.z = (float)xv[2] + (float)ph[2]*sc2 + sh2;
    y.w = (float)xv[3] + (float)ph[3]*sc3 + sh3;
    y.x = y.x > 0.f ? y.x : 0.f; y.y = y.y > 0.f ? y.y : 0.f;
    y.z = y.z > 0.f ? y.z : 0.f; y.w = y.w > 0.f ? y.w : 0.f;
    *(float4*)(out + off) = y;
}

extern "C" void kernel_launch(void* const* d_in, const int* in_sizes, int n_in,
                              void* d_out, int out_size, void* d_ws, size_t ws_size,
                              hipStream_t stream) {
    const float* x     = (const float*)d_in[0];
    const float* Uw    = (const float*)d_in[1];
    const float* Ub    = (const float*)d_in[2];
    const float* Vw    = (const float*)d_in[3];
    const float* Vb    = (const float*)d_in[4];
    const float* gamma = (const float*)d_in[5];
    const float* beta  = (const float*)d_in[6];
    float* out = (float*)d_out;

    // workspace: preh (R*C f16) | nbr (R*4 i32) | stats (256 f32) |
    //            xh (R*C f16) | xl (R*C f16) | Whg (2*C*C f16)
    half_t* preh  = (half_t*)d_ws;
    int*    nbr   = (int*)(preh + (size_t)R_ * C_);
    float*  stats = (float*)(nbr + (size_t)R_ * 4);
    half_t* xh    = (half_t*)(stats + 256);
    half_t* xl    = xh + (size_t)R_ * C_;
    half_t* Whg   = xl + (size_t)R_ * C_;

    hipMemsetAsync(stats, 0, 256 * sizeof(float), stream);
    k_split<<<3104, 256, 0, stream>>>(x, Vw, Uw, xh, xl, Whg);
    k_sim_topk<<<N_ * 8, 512, 0, stream>>>(xh, xl, nbr);
    k_fused<<<384, 512, 0, stream>>>(xh, Whg, Vb, Ub, nbr, preh, stats);
    k_fin<<<(R_ * 32) / 256, 256, 0, stream>>>(xh, preh, stats, gamma, beta, out);
}